// Round 5
// baseline (1031.135 us; speedup 1.0000x reference)
//
#include <hip/hip_runtime.h>

#define DD 128
#define NMESH 30000
#define NOBJ 2000
#define EMMN 240000
#define EMON 60000
#define NB_MM (EMMN / 128)           // 1875
#define NB_MO ((EMON + 127) / 128)   // 469
#define NB_NM ((NMESH + 127) / 128)  // 235
#define NB_NO ((NOBJ + 127) / 128)   // 16

typedef unsigned short u16;
typedef short short8 __attribute__((ext_vector_type(8)));
typedef float f32x4 __attribute__((ext_vector_type(4)));
typedef __bf16 bf16x8 __attribute__((ext_vector_type(8)));

union FragCvt { short8 s; bf16x8 b; };

static __device__ __forceinline__ u16 f2bf(float f) {
  union { float f; unsigned u; } v; v.f = f;
  unsigned r = v.u + 0x7FFFu + ((v.u >> 16) & 1u);
  return (u16)(r >> 16);
}
static __device__ __forceinline__ float bf2f(u16 u) {
  union { unsigned u; float f; } v; v.u = ((unsigned)u) << 16; return v.f;
}
// swizzle: XOR 16B-chunk index with row&7 (byte bits 4..6) -> conflict-free ds_read_b128
static __device__ __forceinline__ int swz256(int row, int b) {
  return row * 256 + (b ^ ((row & 7) << 4));
}
static __device__ __forceinline__ bf16x8 ldsFrag(const u16* s, int row, int kByte) {
  FragCvt u; u.s = *(const short8*)((const char*)s + swz256(row, kByte));
  return u.b;
}

static __device__ __forceinline__ void gload_lds16(const void* g, void* l) {
  __builtin_amdgcn_global_load_lds((const __attribute__((address_space(1))) void*)g,
                                   (__attribute__((address_space(3))) void*)l, 16, 0, 0);
}

// async-stage a 128x128 bf16 weight block into LDS, pre-swizzled global source,
// linear LDS dest (rule #21). 8 waves x 4 iters x 1KB.
static __device__ __forceinline__ void stage_w_async(u16* sW, const u16* W,
                                                     int rowLen, int colOff, int tid) {
  const int w = tid >> 6, lane = tid & 63;
  #pragma unroll
  for (int j = 0; j < 4; ++j) {
    const int base_row = (j * 8 + w) * 4;
    const int row = base_row + (lane >> 4);
    const int chunk = (lane & 15) ^ (row & 7);      // inverse of read swizzle
    const u16* g = W + (size_t)row * rowLen + colOff + chunk * 8;
    gload_lds16(g, (char*)sW + base_row * 256);
  }
}

// one K=128 GEMM part: per wave 32 rows x 64 cols
static __device__ __forceinline__ void mfma_128k(const u16* sIn, const u16* sW,
                                                 int wr, int wc, int lrow, int lk,
                                                 f32x4 acc[2][4]) {
  #pragma unroll
  for (int kc = 0; kc < 4; ++kc) {
    bf16x8 a0 = ldsFrag(sIn, wr * 32 + lrow, kc * 64 + lk * 16);
    bf16x8 a1 = ldsFrag(sIn, wr * 32 + 16 + lrow, kc * 64 + lk * 16);
    #pragma unroll
    for (int ct = 0; ct < 4; ++ct) {
      bf16x8 b = ldsFrag(sW, wc * 64 + ct * 16 + lrow, kc * 64 + lk * 16);
      acc[0][ct] = __builtin_amdgcn_mfma_f32_16x16x32_bf16(a0, b, acc[0][ct], 0, 0, 0);
      acc[1][ct] = __builtin_amdgcn_mfma_f32_16x16x32_bf16(a1, b, acc[1][ct], 0, 0, 0);
    }
  }
}

static __device__ __forceinline__ void transition_relu(u16* sIn, const float* sBias, int biasOff,
                                                       int wr, int wc, int lrow, int lk,
                                                       f32x4 acc[2][4]) {
  #pragma unroll
  for (int rt = 0; rt < 2; ++rt) {
    #pragma unroll
    for (int ct = 0; ct < 4; ++ct) {
      const int col = wc * 64 + ct * 16 + lrow;
      const float bias = sBias[biasOff + col];
      #pragma unroll
      for (int r = 0; r < 4; ++r) {
        const int orow = wr * 32 + rt * 16 + lk * 4 + r;
        float v = acc[rt][ct][r] + bias;
        v = fmaxf(v, 0.f);
        *(u16*)((char*)sIn + swz256(orow, col * 2)) = f2bf(v);
        acc[rt][ct][r] = 0.f;
      }
    }
  }
}

// in-register LayerNorm from accumulators; result (bf16) staged into sIn.
// contains one __syncthreads (uniform).
static __device__ __forceinline__ void ln_to_sIn(u16* sIn, float* sPart, const float* sBias,
                                                 int wr, int wc, int lrow, int lk,
                                                 f32x4 acc[2][4]) {
  float gv[4], bv[4];
  #pragma unroll
  for (int ct = 0; ct < 4; ++ct) {
    const int col = wc * 64 + ct * 16 + lrow;
    gv[ct] = sBias[384 + col];
    bv[ct] = sBias[512 + col];
  }
  float s1[2][4], s2[2][4];
  #pragma unroll
  for (int rt = 0; rt < 2; ++rt) {
    #pragma unroll
    for (int r = 0; r < 4; ++r) {
      float a = 0.f, b = 0.f;
      #pragma unroll
      for (int ct = 0; ct < 4; ++ct) {
        const int col = wc * 64 + ct * 16 + lrow;
        const float v = acc[rt][ct][r] + sBias[256 + col];  // + b2
        acc[rt][ct][r] = v;
        a += v; b += v * v;
      }
      #pragma unroll
      for (int m = 1; m < 16; m <<= 1) { a += __shfl_xor(a, m); b += __shfl_xor(b, m); }
      s1[rt][r] = a; s2[rt][r] = b;   // wc-half sums, same edge across the 16-lane group
    }
  }
  if (lrow == 0) {
    #pragma unroll
    for (int rt = 0; rt < 2; ++rt)
      #pragma unroll
      for (int r = 0; r < 4; ++r) {
        const int e = wr * 32 + rt * 16 + lk * 4 + r;
        sPart[(wc * 128 + e) * 2] = s1[rt][r];
        sPart[(wc * 128 + e) * 2 + 1] = s2[rt][r];
      }
  }
  __syncthreads();
  #pragma unroll
  for (int rt = 0; rt < 2; ++rt)
    #pragma unroll
    for (int r = 0; r < 4; ++r) {
      const int e = wr * 32 + rt * 16 + lk * 4 + r;
      const float t1 = s1[rt][r] + sPart[((1 - wc) * 128 + e) * 2];
      const float t2 = s2[rt][r] + sPart[((1 - wc) * 128 + e) * 2 + 1];
      const float m = t1 * (1.f / 128.f);
      const float var = t2 * (1.f / 128.f) - m * m;
      const float rstd = rsqrtf(var + 1e-5f);
      #pragma unroll
      for (int ct = 0; ct < 4; ++ct) {
        const int col = wc * 64 + ct * 16 + lrow;
        const float ln = (acc[rt][ct][r] - m) * rstd * gv[ct] + bv[ct];
        *(u16*)((char*)sIn + swz256(e, col * 2)) = f2bf(ln);
      }
    }
}

static __device__ __forceinline__ void stage_rows_bf(u16* sIn, const u16* src, int row, int seg) {
  #pragma unroll
  for (int j = 0; j < 4; ++j) {
    short8 v = *(const short8*)(src + seg * 32 + j * 8);
    *(short8*)((char*)sIn + swz256(row, seg * 64 + j * 16)) = v;
  }
}
static __device__ __forceinline__ void stage_rows_f32(u16* sIn, const float* src, int row, int seg) {
  #pragma unroll
  for (int j = 0; j < 4; ++j) {
    const int c0 = seg * 32 + j * 8;
    f32x4 f0 = *(const f32x4*)(src + c0);
    f32x4 f1 = *(const f32x4*)(src + c0 + 4);
    short8 v;
    #pragma unroll
    for (int q = 0; q < 4; ++q) { v[q] = (short)f2bf(f0[q]); v[4 + q] = (short)f2bf(f1[q]); }
    *(short8*)((char*)sIn + swz256(row, seg * 64 + j * 16)) = v;
  }
}

// ---------------- edge conv body (128 edges / block, 8 waves)
static __device__ void edge_body(int bid,
    const u16* xsrc, const u16* xdst, const int* ei, int E,
    const float* ea_f32, u16* ea_bf,
    const u16* W0T, const u16* W1T, const u16* W2T,
    const float* b0, const float* b1, const float* b2,
    const float* gq, const float* btq, u16* msg_out,
    u16* sIn, u16* sW, float* sBias, float* sPart)
{
  const int tid = threadIdx.x;
  const int wave = tid >> 6, lane = tid & 63;
  const int lrow = lane & 15, lk = lane >> 4;
  const int wr = wave >> 1, wc = wave & 1;
  const int e0 = bid * 128;
  const int row = tid >> 2, seg = tid & 3;
  const int eRow = (e0 + row < E) ? (e0 + row) : (E - 1);

  if (tid < 128) {
    sBias[tid] = b0[tid];
    sBias[128 + tid] = b1[tid];
    sBias[256 + tid] = b2[tid];
    sBias[384 + tid] = gq[tid];
    sBias[512 + tid] = btq[tid];
  }

  const f32x4 zero = {0.f, 0.f, 0.f, 0.f};
  f32x4 acc[2][4];
  #pragma unroll
  for (int i = 0; i < 2; ++i)
    #pragma unroll
    for (int j = 0; j < 4; ++j) acc[i][j] = zero;

  // layer 1: three K=128 parts (x_dst, x_src, ea)
  stage_w_async(sW, W0T, 384, 0, tid);
  { const int idx = ei[E + eRow]; stage_rows_bf(sIn, xdst + (size_t)idx * DD, row, seg); }
  __syncthreads();
  mfma_128k(sIn, sW, wr, wc, lrow, lk, acc);
  __syncthreads();

  stage_w_async(sW, W0T, 384, 128, tid);
  { const int idx = ei[eRow]; stage_rows_bf(sIn, xsrc + (size_t)idx * DD, row, seg); }
  __syncthreads();
  mfma_128k(sIn, sW, wr, wc, lrow, lk, acc);
  __syncthreads();

  stage_w_async(sW, W0T, 384, 256, tid);
  if (ea_f32) stage_rows_f32(sIn, ea_f32 + (size_t)eRow * DD, row, seg);
  else        stage_rows_bf(sIn, ea_bf + (size_t)eRow * DD, row, seg);
  __syncthreads();
  mfma_128k(sIn, sW, wr, wc, lrow, lk, acc);
  __syncthreads();

  transition_relu(sIn, sBias, 0, wr, wc, lrow, lk, acc);
  stage_w_async(sW, W1T, 128, 0, tid);
  __syncthreads();
  mfma_128k(sIn, sW, wr, wc, lrow, lk, acc);
  __syncthreads();

  transition_relu(sIn, sBias, 128, wr, wc, lrow, lk, acc);
  stage_w_async(sW, W2T, 128, 0, tid);
  __syncthreads();
  mfma_128k(sIn, sW, wr, wc, lrow, lk, acc);
  __syncthreads();

  ln_to_sIn(sIn, sPart, sBias, wr, wc, lrow, lk, acc);
  __syncthreads();

  // epilogue: msg (bf16, nt) + ea residual (bf16, nt); coalesced 16B stores
  const int e = e0 + row;
  if (e < E) {
    short8 msgv[4];
    #pragma unroll
    for (int j = 0; j < 4; ++j)
      msgv[j] = *(const short8*)((const char*)sIn + swz256(row, seg * 64 + j * 16));
    u16* msgRow = msg_out + (size_t)e * DD + seg * 32;
    u16* eaRow  = ea_bf + (size_t)e * DD + seg * 32;
    if (ea_f32) {
      const float* er = ea_f32 + (size_t)e * DD + seg * 32;
      #pragma unroll
      for (int j = 0; j < 4; ++j) {
        f32x4 o0 = __builtin_nontemporal_load((const f32x4*)(er + j * 8));
        f32x4 o1 = __builtin_nontemporal_load((const f32x4*)(er + j * 8 + 4));
        short8 en;
        #pragma unroll
        for (int q = 0; q < 4; ++q) {
          en[q]     = (short)f2bf(o0[q] + bf2f((u16)msgv[j][q]));
          en[4 + q] = (short)f2bf(o1[q] + bf2f((u16)msgv[j][4 + q]));
        }
        __builtin_nontemporal_store(en, (short8*)(eaRow + j * 8));
        __builtin_nontemporal_store(msgv[j], (short8*)(msgRow + j * 8));
      }
    } else {
      #pragma unroll
      for (int j = 0; j < 4; ++j) {
        short8 old = __builtin_nontemporal_load((const short8*)(eaRow + j * 8));
        short8 en;
        #pragma unroll
        for (int q = 0; q < 8; ++q)
          en[q] = (short)f2bf(bf2f((u16)old[q]) + bf2f((u16)msgv[j][q]));
        __builtin_nontemporal_store(en, (short8*)(eaRow + j * 8));
        __builtin_nontemporal_store(msgv[j], (short8*)(msgRow + j * 8));
      }
    }
  }
}

__global__ __launch_bounds__(512, 4) void edge_conv_kernel(
    const u16* __restrict__ xm_bf, const u16* __restrict__ xo_bf,
    const int* __restrict__ ei_mm, const int* __restrict__ ei_mo,
    const float* __restrict__ eaf_mm, const float* __restrict__ eaf_mo,
    u16* __restrict__ eab_mm, u16* __restrict__ eab_mo,
    const u16* __restrict__ W0a, const u16* __restrict__ W1a, const u16* __restrict__ W2a,
    const u16* __restrict__ W0b, const u16* __restrict__ W1b, const u16* __restrict__ W2b,
    const float* __restrict__ b0a, const float* __restrict__ b1a, const float* __restrict__ b2a,
    const float* __restrict__ ga, const float* __restrict__ bta,
    const float* __restrict__ b0b, const float* __restrict__ b1b, const float* __restrict__ b2b,
    const float* __restrict__ gb, const float* __restrict__ btb,
    u16* __restrict__ msg_mm, u16* __restrict__ msg_mo)
{
  __shared__ u16 sIn[128 * 128];
  __shared__ u16 sW[128 * 128];
  __shared__ float sBias[5 * 128];
  __shared__ float sPart[2 * 128 * 2];
  if ((int)blockIdx.x < NB_MM)
    edge_body(blockIdx.x, xm_bf, xm_bf, ei_mm, EMMN, eaf_mm, eab_mm,
              W0a, W1a, W2a, b0a, b1a, b2a, ga, bta, msg_mm, sIn, sW, sBias, sPart);
  else
    edge_body(blockIdx.x - NB_MM, xm_bf, xo_bf, ei_mo, EMON, eaf_mo, eab_mo,
              W0b, W1b, W2b, b0b, b1b, b2b, gb, btb, msg_mo, sIn, sW, sBias, sPart);
}

// ---------------- node conv body (128 nodes / block)
static __device__ void node_body(int bid, u16* x_bf, const float* aggin, float* x_f32, int N,
    const u16* W0T, const u16* W1T, const u16* W2T,
    const float* b0, const float* b1, const float* b2,
    const float* gq, const float* btq,
    u16* sIn, u16* sW, float* sBias, float* sPart)
{
  const int tid = threadIdx.x;
  const int wave = tid >> 6, lane = tid & 63;
  const int lrow = lane & 15, lk = lane >> 4;
  const int wr = wave >> 1, wc = wave & 1;
  const int n0 = bid * 128;
  const int row = tid >> 2, seg = tid & 3;
  const int nRow = (n0 + row < N) ? (n0 + row) : (N - 1);

  if (tid < 128) {
    sBias[tid] = b0[tid];
    sBias[128 + tid] = b1[tid];
    sBias[256 + tid] = b2[tid];
    sBias[384 + tid] = gq[tid];
    sBias[512 + tid] = btq[tid];
  }

  const f32x4 zero = {0.f, 0.f, 0.f, 0.f};
  f32x4 acc[2][4];
  #pragma unroll
  for (int i = 0; i < 2; ++i)
    #pragma unroll
    for (int j = 0; j < 4; ++j) acc[i][j] = zero;

  stage_w_async(sW, W0T, 256, 0, tid);
  stage_rows_bf(sIn, x_bf + (size_t)nRow * DD, row, seg);
  __syncthreads();
  mfma_128k(sIn, sW, wr, wc, lrow, lk, acc);
  __syncthreads();

  stage_w_async(sW, W0T, 256, 128, tid);
  stage_rows_f32(sIn, aggin + (size_t)nRow * DD, row, seg);
  __syncthreads();
  mfma_128k(sIn, sW, wr, wc, lrow, lk, acc);
  __syncthreads();

  transition_relu(sIn, sBias, 0, wr, wc, lrow, lk, acc);
  stage_w_async(sW, W1T, 128, 0, tid);
  __syncthreads();
  mfma_128k(sIn, sW, wr, wc, lrow, lk, acc);
  __syncthreads();

  transition_relu(sIn, sBias, 128, wr, wc, lrow, lk, acc);
  stage_w_async(sW, W2T, 128, 0, tid);
  __syncthreads();
  mfma_128k(sIn, sW, wr, wc, lrow, lk, acc);
  __syncthreads();

  ln_to_sIn(sIn, sPart, sBias, wr, wc, lrow, lk, acc);
  __syncthreads();

  // epilogue: x_f32 += ln ; refresh x_bf
  const int n = n0 + row;
  if (n < N) {
    short8 lnv[4];
    #pragma unroll
    for (int j = 0; j < 4; ++j)
      lnv[j] = *(const short8*)((const char*)sIn + swz256(row, seg * 64 + j * 16));
    float* xr = x_f32 + (size_t)n * DD + seg * 32;
    u16* xb = x_bf + (size_t)n * DD + seg * 32;
    #pragma unroll
    for (int j = 0; j < 4; ++j) {
      f32x4 o0 = *(const f32x4*)(xr + j * 8);
      f32x4 o1 = *(const f32x4*)(xr + j * 8 + 4);
      f32x4 n0v, n1v;
      short8 pb;
      #pragma unroll
      for (int q = 0; q < 4; ++q) {
        n0v[q] = o0[q] + bf2f((u16)lnv[j][q]);
        n1v[q] = o1[q] + bf2f((u16)lnv[j][4 + q]);
        pb[q]     = (short)f2bf(n0v[q]);
        pb[4 + q] = (short)f2bf(n1v[q]);
      }
      *(f32x4*)(xr + j * 8) = n0v;
      *(f32x4*)(xr + j * 8 + 4) = n1v;
      *(short8*)(xb + j * 8) = pb;
    }
  }
}

__global__ __launch_bounds__(512, 4) void node_conv_kernel(
    u16* __restrict__ xm_bf, u16* __restrict__ xo_bf,
    const float* __restrict__ agg_m, const float* __restrict__ agg_o,
    float* __restrict__ xf_m, float* __restrict__ xf_o,
    const u16* __restrict__ W0a, const u16* __restrict__ W1a, const u16* __restrict__ W2a,
    const u16* __restrict__ W0b, const u16* __restrict__ W1b, const u16* __restrict__ W2b,
    const float* __restrict__ b0a, const float* __restrict__ b1a, const float* __restrict__ b2a,
    const float* __restrict__ ga, const float* __restrict__ bta,
    const float* __restrict__ b0b, const float* __restrict__ b1b, const float* __restrict__ b2b,
    const float* __restrict__ gb, const float* __restrict__ btb)
{
  __shared__ u16 sIn[128 * 128];
  __shared__ u16 sW[128 * 128];
  __shared__ float sBias[5 * 128];
  __shared__ float sPart[2 * 128 * 2];
  if ((int)blockIdx.x < NB_NM)
    node_body(blockIdx.x, xm_bf, agg_m, xf_m, NMESH,
              W0a, W1a, W2a, b0a, b1a, b2a, ga, bta, sIn, sW, sBias, sPart);
  else
    node_body(blockIdx.x - NB_NM, xo_bf, agg_o, xf_o, NOBJ,
              W0b, W1b, W2b, b0b, b1b, b2b, gb, btb, sIn, sW, sBias, sPart);
}

// ---------------- CSR build ----------------
__global__ void hist_kernel(const int* __restrict__ ei_mm, const int* __restrict__ ei_mo,
                            int* __restrict__ deg_m, int* __restrict__ deg_o) {
  int i = blockIdx.x * blockDim.x + threadIdx.x;
  if (i < EMMN) atomicAdd(&deg_m[ei_mm[EMMN + i]], 1);
  else { int j = i - EMMN; if (j < EMON) atomicAdd(&deg_o[ei_mo[EMON + j]], 1); }
}

__global__ __launch_bounds__(1024) void scan_kernel(
    const int* __restrict__ deg_m, int* __restrict__ start_m, int* __restrict__ cur_m,
    const int* __restrict__ deg_o, int* __restrict__ start_o, int* __restrict__ cur_o) {
  const int* deg; int* start; int* cursor; int N;
  if (blockIdx.x == 0) { deg = deg_m; start = start_m; cursor = cur_m; N = NMESH; }
  else                 { deg = deg_o; start = start_o; cursor = cur_o; N = NOBJ; }
  __shared__ int lds[1024];
  const int t = threadIdx.x;
  const int chunk = (N + 1023) >> 10;
  const int base = t * chunk;
  const int end = min(base + chunk, N);
  int s = 0;
  for (int i = base; i < end; ++i) s += deg[i];
  lds[t] = s;
  __syncthreads();
  for (int d = 1; d < 1024; d <<= 1) {
    int v = (t >= d) ? lds[t - d] : 0;
    __syncthreads();
    lds[t] += v;
    __syncthreads();
  }
  int off = lds[t] - s;
  for (int i = base; i < end; ++i) { start[i] = off; cursor[i] = off; off += deg[i]; }
  if (t == 1023) start[N] = lds[1023];
}

__global__ void scatter_kernel(const int* __restrict__ ei_mm, const int* __restrict__ ei_mo,
                               int* __restrict__ cur_m, int* __restrict__ cur_o,
                               int* __restrict__ perm_m, int* __restrict__ perm_o) {
  int i = blockIdx.x * blockDim.x + threadIdx.x;
  if (i < EMMN) { int p = atomicAdd(&cur_m[ei_mm[EMMN + i]], 1); perm_m[p] = i; }
  else { int j = i - EMMN; if (j < EMON) { int p = atomicAdd(&cur_o[ei_mo[EMON + j]], 1); perm_o[p] = j; } }
}

// ---------------- aggregate (CSR gather), mesh+obj merged
__global__ __launch_bounds__(256) void agg_gather_kernel(
    const u16* __restrict__ msg_m, const int* __restrict__ start_m, const int* __restrict__ perm_m,
    float* __restrict__ agg_m,
    const u16* __restrict__ msg_o, const int* __restrict__ start_o, const int* __restrict__ perm_o,
    float* __restrict__ agg_o)
{
  const int wave = threadIdx.x >> 6, lane = threadIdx.x & 63;
  int idx = blockIdx.x * 4 + wave;
  const u16* msg; const int* start; const int* perm; float* agg; int n;
  if (idx < NMESH) { msg = msg_m; start = start_m; perm = perm_m; agg = agg_m; n = idx; }
  else {
    n = idx - NMESH;
    if (n >= NOBJ) return;
    msg = msg_o; start = start_o; perm = perm_o; agg = agg_o;
  }
  const int i0 = start[n], i1 = start[n + 1];
  float a0 = 0.f, a1 = 0.f;
  int i = i0;
  for (; i + 1 < i1; i += 2) {
    const int e1 = perm[i], e2 = perm[i + 1];
    unsigned v1 = __builtin_nontemporal_load((const unsigned*)(msg + (size_t)e1 * DD + lane * 2));
    unsigned v2 = __builtin_nontemporal_load((const unsigned*)(msg + (size_t)e2 * DD + lane * 2));
    a0 += bf2f((u16)(v1 & 0xFFFFu)) + bf2f((u16)(v2 & 0xFFFFu));
    a1 += bf2f((u16)(v1 >> 16)) + bf2f((u16)(v2 >> 16));
  }
  if (i < i1) {
    const int e1 = perm[i];
    unsigned v1 = __builtin_nontemporal_load((const unsigned*)(msg + (size_t)e1 * DD + lane * 2));
    a0 += bf2f((u16)(v1 & 0xFFFFu));
    a1 += bf2f((u16)(v1 >> 16));
  }
  float* ar = agg + (size_t)n * DD + lane * 2;
  ar[0] = a0;
  ar[1] = a1;
}

// ---------------- one merged prep kernel ----------------
static __device__ __forceinline__ void wcvt(const float* src, u16* dst, int K, int b, int t) {
  int i = b * 256 + t;
  int n = i & 127;
  int k = (i >> 7) % K;
  int sl = i / (K * 128);
  dst[((size_t)sl * 128 + n) * K + k] = f2bf(src[i]);
}

__global__ void prep_kernel(
    const float* __restrict__ eW0, const float* __restrict__ eW1, const float* __restrict__ eW2,
    const float* __restrict__ nW0, const float* __restrict__ nW1, const float* __restrict__ nW2,
    u16* __restrict__ eW0T, u16* __restrict__ eW1T, u16* __restrict__ eW2T,
    u16* __restrict__ nW0T, u16* __restrict__ nW1T, u16* __restrict__ nW2T,
    int* __restrict__ deg_m, int* __restrict__ deg_o,
    const float* __restrict__ xm, const float* __restrict__ xo,
    float* __restrict__ xf, u16* __restrict__ xmb, u16* __restrict__ xob)
{
  const int b = blockIdx.x, t = threadIdx.x;
  if (b < 768)        wcvt(eW0, eW0T, 384, b, t);
  else if (b < 1024)  wcvt(eW1, eW1T, 128, b - 768, t);
  else if (b < 1280)  wcvt(eW2, eW2T, 128, b - 1024, t);
  else if (b < 1792)  wcvt(nW0, nW0T, 256, b - 1280, t);
  else if (b < 2048)  wcvt(nW1, nW1T, 128, b - 1792, t);
  else if (b < 2304)  wcvt(nW2, nW2T, 128, b - 2048, t);
  else if (b < 2429) {
    int i = (b - 2304) * 256 + t;
    if (i < NMESH) deg_m[i] = 0;
    else if (i < NMESH + NOBJ) deg_o[i - NMESH] = 0;
  } else {
    int i = (b - 2429) * 256 + t;
    const int tm = NMESH * DD;
    if (i < tm) { float v = xm[i]; xf[i] = v; xmb[i] = f2bf(v); }
    else { int j = i - tm; float v = xo[j]; xf[tm + j] = v; xob[j] = f2bf(v); }
  }
}

extern "C" void kernel_launch(void* const* d_in, const int* in_sizes, int n_in,
                              void* d_out, int out_size, void* d_ws, size_t ws_size,
                              hipStream_t stream)
{
  const float* x_mesh = (const float*)d_in[0];
  const float* x_obj  = (const float*)d_in[1];
  const int*   ei_mm  = (const int*)d_in[2];
  const int*   ei_mo  = (const int*)d_in[3];
  const float* ea_mm  = (const float*)d_in[4];
  const float* ea_mo  = (const float*)d_in[5];
  const float* eW0 = (const float*)d_in[6];
  const float* eb0 = (const float*)d_in[7];
  const float* eW1 = (const float*)d_in[8];
  const float* eb1 = (const float*)d_in[9];
  const float* eW2 = (const float*)d_in[10];
  const float* eb2 = (const float*)d_in[11];
  const float* eg  = (const float*)d_in[12];
  const float* ebt = (const float*)d_in[13];
  const float* nW0 = (const float*)d_in[14];
  const float* nb0 = (const float*)d_in[15];
  const float* nW1 = (const float*)d_in[16];
  const float* nb1 = (const float*)d_in[17];
  const float* nW2 = (const float*)d_in[18];
  const float* nb2 = (const float*)d_in[19];
  const float* ng  = (const float*)d_in[20];
  const float* nbt = (const float*)d_in[21];

  u16* eamm_bf = (u16*)d_ws;
  u16* eamo_bf = eamm_bf + (size_t)EMMN * DD;
  u16* xm_bf   = eamo_bf + (size_t)EMON * DD;
  u16* xo_bf   = xm_bf + (size_t)NMESH * DD;
  float* agg_m = (float*)(xo_bf + (size_t)NOBJ * DD);
  float* agg_o = agg_m + (size_t)NMESH * DD;
  u16* eW0T = (u16*)(agg_o + (size_t)NOBJ * DD);
  u16* eW1T = eW0T + (size_t)4 * 128 * 384;
  u16* eW2T = eW1T + (size_t)4 * 128 * 128;
  u16* nW0T = eW2T + (size_t)4 * 128 * 128;
  u16* nW1T = nW0T + (size_t)4 * 128 * 256;
  u16* nW2T = nW1T + (size_t)4 * 128 * 128;
  u16* msg_mm = nW2T + (size_t)4 * 128 * 128;
  u16* msg_mo = msg_mm + (size_t)EMMN * DD;
  int* deg_m   = (int*)(msg_mo + (size_t)EMON * DD);
  int* start_m = deg_m + NMESH;
  int* cur_m   = start_m + NMESH + 1;
  int* perm_mm = cur_m + NMESH;
  int* deg_o   = perm_mm + EMMN;
  int* start_o = deg_o + NOBJ;
  int* cur_o   = start_o + NOBJ + 1;
  int* perm_mo = cur_o + NOBJ;

  float* xf_m = (float*)d_out;
  float* xf_o = xf_m + (size_t)NMESH * DD;

  prep_kernel<<<18429, 256, 0, stream>>>(eW0, eW1, eW2, nW0, nW1, nW2,
                                         eW0T, eW1T, eW2T, nW0T, nW1T, nW2T,
                                         deg_m, deg_o, x_mesh, x_obj, xf_m, xm_bf, xo_bf);
  hist_kernel<<<(EMMN + EMON + 255) / 256, 256, 0, stream>>>(ei_mm, ei_mo, deg_m, deg_o);
  scan_kernel<<<2, 1024, 0, stream>>>(deg_m, start_m, cur_m, deg_o, start_o, cur_o);
  scatter_kernel<<<(EMMN + EMON + 255) / 256, 256, 0, stream>>>(ei_mm, ei_mo, cur_m, cur_o,
                                                                perm_mm, perm_mo);

  for (int s = 0; s < 2; ++s) {
    const int sa = 0 * 2 + s, sb = 1 * 2 + s;
    edge_conv_kernel<<<NB_MM + NB_MO, 512, 0, stream>>>(
        xm_bf, xo_bf, ei_mm, ei_mo,
        (s == 0) ? ea_mm : (const float*)nullptr,
        (s == 0) ? ea_mo : (const float*)nullptr,
        eamm_bf, eamo_bf,
        eW0T + (size_t)sa * 128 * 384, eW1T + (size_t)sa * 128 * 128, eW2T + (size_t)sa * 128 * 128,
        eW0T + (size_t)sb * 128 * 384, eW1T + (size_t)sb * 128 * 128, eW2T + (size_t)sb * 128 * 128,
        eb0 + sa * 128, eb1 + sa * 128, eb2 + sa * 128, eg + sa * 128, ebt + sa * 128,
        eb0 + sb * 128, eb1 + sb * 128, eb2 + sb * 128, eg + sb * 128, ebt + sb * 128,
        msg_mm, msg_mo);
    agg_gather_kernel<<<(NMESH + NOBJ + 3) / 4, 256, 0, stream>>>(
        msg_mm, start_m, perm_mm, agg_m, msg_mo, start_o, perm_mo, agg_o);
    node_conv_kernel<<<NB_NM + NB_NO, 512, 0, stream>>>(
        xm_bf, xo_bf, agg_m, agg_o, xf_m, xf_o,
        nW0T + (size_t)sa * 128 * 256, nW1T + (size_t)sa * 128 * 128, nW2T + (size_t)sa * 128 * 128,
        nW0T + (size_t)sb * 128 * 256, nW1T + (size_t)sb * 128 * 128, nW2T + (size_t)sb * 128 * 128,
        nb0 + sa * 128, nb1 + sa * 128, nb2 + sa * 128, ng + sa * 128, nbt + sa * 128,
        nb0 + sb * 128, nb1 + sb * 128, nb2 + sb * 128, ng + sb * 128, nbt + sb * 128);
  }
}

// Round 6
// 745.911 us; speedup vs baseline: 1.3824x; 1.3824x over previous
//
#include <hip/hip_runtime.h>

#define DD 128
#define NMESH 30000
#define NOBJ 2000
#define EMMN 240000
#define EMON 60000
#define NB_MM (EMMN / 128)           // 1875
#define NB_MO ((EMON + 127) / 128)   // 469
#define NB_NM ((NMESH + 127) / 128)  // 235
#define NB_NO ((NOBJ + 127) / 128)   // 16

typedef unsigned short u16;
typedef short short8 __attribute__((ext_vector_type(8)));
typedef float f32x4 __attribute__((ext_vector_type(4)));
typedef __bf16 bf16x8 __attribute__((ext_vector_type(8)));

union FragCvt { short8 s; bf16x8 b; };

static __device__ __forceinline__ u16 f2bf(float f) {
  union { float f; unsigned u; } v; v.f = f;
  unsigned r = v.u + 0x7FFFu + ((v.u >> 16) & 1u);
  return (u16)(r >> 16);
}
static __device__ __forceinline__ float bf2f(u16 u) {
  union { unsigned u; float f; } v; v.u = ((unsigned)u) << 16; return v.f;
}
// swizzle: XOR 16B-chunk index with row&7 (byte bits 4..6) -> conflict-free ds_read_b128
static __device__ __forceinline__ int swz256(int row, int b) {
  return row * 256 + (b ^ ((row & 7) << 4));
}
static __device__ __forceinline__ bf16x8 ldsFrag(const u16* s, int row, int kByte) {
  FragCvt u; u.s = *(const short8*)((const char*)s + swz256(row, kByte));
  return u.b;
}

static __device__ __forceinline__ void gload_lds16(const void* g, void* l) {
  __builtin_amdgcn_global_load_lds((const __attribute__((address_space(1))) void*)g,
                                   (__attribute__((address_space(3))) void*)l, 16, 0, 0);
}

// async-stage a 128x128 bf16 weight block into LDS, pre-swizzled global source,
// linear LDS dest (rule #21). 8 waves x 4 iters x 1KB.
static __device__ __forceinline__ void stage_w_async(u16* sW, const u16* W,
                                                     int rowLen, int colOff, int tid) {
  const int w = tid >> 6, lane = tid & 63;
  #pragma unroll
  for (int j = 0; j < 4; ++j) {
    const int base_row = (j * 8 + w) * 4;
    const int row = base_row + (lane >> 4);
    const int chunk = (lane & 15) ^ (row & 7);      // inverse of read swizzle
    const u16* g = W + (size_t)row * rowLen + colOff + chunk * 8;
    gload_lds16(g, (char*)sW + base_row * 256);
  }
}

// one K=128 GEMM part: per wave 32 rows x 64 cols
static __device__ __forceinline__ void mfma_128k(const u16* sIn, const u16* sW,
                                                 int wr, int wc, int lrow, int lk,
                                                 f32x4 acc[2][4]) {
  #pragma unroll
  for (int kc = 0; kc < 4; ++kc) {
    bf16x8 a0 = ldsFrag(sIn, wr * 32 + lrow, kc * 64 + lk * 16);
    bf16x8 a1 = ldsFrag(sIn, wr * 32 + 16 + lrow, kc * 64 + lk * 16);
    #pragma unroll
    for (int ct = 0; ct < 4; ++ct) {
      bf16x8 b = ldsFrag(sW, wc * 64 + ct * 16 + lrow, kc * 64 + lk * 16);
      acc[0][ct] = __builtin_amdgcn_mfma_f32_16x16x32_bf16(a0, b, acc[0][ct], 0, 0, 0);
      acc[1][ct] = __builtin_amdgcn_mfma_f32_16x16x32_bf16(a1, b, acc[1][ct], 0, 0, 0);
    }
  }
}

static __device__ __forceinline__ void transition_relu(u16* sIn, const float* sBias, int biasOff,
                                                       int wr, int wc, int lrow, int lk,
                                                       f32x4 acc[2][4]) {
  #pragma unroll
  for (int rt = 0; rt < 2; ++rt) {
    #pragma unroll
    for (int ct = 0; ct < 4; ++ct) {
      const int col = wc * 64 + ct * 16 + lrow;
      const float bias = sBias[biasOff + col];
      #pragma unroll
      for (int r = 0; r < 4; ++r) {
        const int orow = wr * 32 + rt * 16 + lk * 4 + r;
        float v = acc[rt][ct][r] + bias;
        v = fmaxf(v, 0.f);
        *(u16*)((char*)sIn + swz256(orow, col * 2)) = f2bf(v);
        acc[rt][ct][r] = 0.f;
      }
    }
  }
}

// in-register LayerNorm from accumulators; result (bf16) staged into sIn.
// contains one __syncthreads (uniform).
static __device__ __forceinline__ void ln_to_sIn(u16* sIn, float* sPart, const float* sBias,
                                                 int wr, int wc, int lrow, int lk,
                                                 f32x4 acc[2][4]) {
  float gv[4], bv[4];
  #pragma unroll
  for (int ct = 0; ct < 4; ++ct) {
    const int col = wc * 64 + ct * 16 + lrow;
    gv[ct] = sBias[384 + col];
    bv[ct] = sBias[512 + col];
  }
  float s1[2][4], s2[2][4];
  #pragma unroll
  for (int rt = 0; rt < 2; ++rt) {
    #pragma unroll
    for (int r = 0; r < 4; ++r) {
      float a = 0.f, b = 0.f;
      #pragma unroll
      for (int ct = 0; ct < 4; ++ct) {
        const int col = wc * 64 + ct * 16 + lrow;
        const float v = acc[rt][ct][r] + sBias[256 + col];  // + b2
        acc[rt][ct][r] = v;
        a += v; b += v * v;
      }
      #pragma unroll
      for (int m = 1; m < 16; m <<= 1) { a += __shfl_xor(a, m); b += __shfl_xor(b, m); }
      s1[rt][r] = a; s2[rt][r] = b;   // wc-half sums, same edge across the 16-lane group
    }
  }
  if (lrow == 0) {
    #pragma unroll
    for (int rt = 0; rt < 2; ++rt)
      #pragma unroll
      for (int r = 0; r < 4; ++r) {
        const int e = wr * 32 + rt * 16 + lk * 4 + r;
        sPart[(wc * 128 + e) * 2] = s1[rt][r];
        sPart[(wc * 128 + e) * 2 + 1] = s2[rt][r];
      }
  }
  __syncthreads();
  #pragma unroll
  for (int rt = 0; rt < 2; ++rt)
    #pragma unroll
    for (int r = 0; r < 4; ++r) {
      const int e = wr * 32 + rt * 16 + lk * 4 + r;
      const float t1 = s1[rt][r] + sPart[((1 - wc) * 128 + e) * 2];
      const float t2 = s2[rt][r] + sPart[((1 - wc) * 128 + e) * 2 + 1];
      const float m = t1 * (1.f / 128.f);
      const float var = t2 * (1.f / 128.f) - m * m;
      const float rstd = rsqrtf(var + 1e-5f);
      #pragma unroll
      for (int ct = 0; ct < 4; ++ct) {
        const int col = wc * 64 + ct * 16 + lrow;
        const float ln = (acc[rt][ct][r] - m) * rstd * gv[ct] + bv[ct];
        *(u16*)((char*)sIn + swz256(e, col * 2)) = f2bf(ln);
      }
    }
}

static __device__ __forceinline__ void stage_rows_bf(u16* sIn, const u16* src, int row, int seg) {
  #pragma unroll
  for (int j = 0; j < 4; ++j) {
    short8 v = *(const short8*)(src + seg * 32 + j * 8);
    *(short8*)((char*)sIn + swz256(row, seg * 64 + j * 16)) = v;
  }
}
static __device__ __forceinline__ void stage_rows_f32(u16* sIn, const float* src, int row, int seg) {
  #pragma unroll
  for (int j = 0; j < 4; ++j) {
    const int c0 = seg * 32 + j * 8;
    f32x4 f0 = *(const f32x4*)(src + c0);
    f32x4 f1 = *(const f32x4*)(src + c0 + 4);
    short8 v;
    #pragma unroll
    for (int q = 0; q < 4; ++q) { v[q] = (short)f2bf(f0[q]); v[4 + q] = (short)f2bf(f1[q]); }
    *(short8*)((char*)sIn + swz256(row, seg * 64 + j * 16)) = v;
  }
}

// ---------------- edge conv body (128 edges / block, 8 waves)
static __device__ void edge_body(int bid,
    const u16* xsrc, const u16* xdst, const int* ei, int E,
    const float* ea_f32, u16* ea_bf,
    const u16* W0T, const u16* W1T, const u16* W2T,
    const float* b0, const float* b1, const float* b2,
    const float* gq, const float* btq, u16* msg_out,
    u16* sIn, u16* sW, float* sBias, float* sPart)
{
  const int tid = threadIdx.x;
  const int wave = tid >> 6, lane = tid & 63;
  const int lrow = lane & 15, lk = lane >> 4;
  const int wr = wave >> 1, wc = wave & 1;
  const int e0 = bid * 128;
  const int row = tid >> 2, seg = tid & 3;
  const int eRow = (e0 + row < E) ? (e0 + row) : (E - 1);

  if (tid < 128) {
    sBias[tid] = b0[tid];
    sBias[128 + tid] = b1[tid];
    sBias[256 + tid] = b2[tid];
    sBias[384 + tid] = gq[tid];
    sBias[512 + tid] = btq[tid];
  }

  const f32x4 zero = {0.f, 0.f, 0.f, 0.f};
  f32x4 acc[2][4];
  #pragma unroll
  for (int i = 0; i < 2; ++i)
    #pragma unroll
    for (int j = 0; j < 4; ++j) acc[i][j] = zero;

  // layer 1: three K=128 parts (x_dst, x_src, ea)
  stage_w_async(sW, W0T, 384, 0, tid);
  { const int idx = ei[E + eRow]; stage_rows_bf(sIn, xdst + (size_t)idx * DD, row, seg); }
  __syncthreads();
  mfma_128k(sIn, sW, wr, wc, lrow, lk, acc);
  __syncthreads();

  stage_w_async(sW, W0T, 384, 128, tid);
  { const int idx = ei[eRow]; stage_rows_bf(sIn, xsrc + (size_t)idx * DD, row, seg); }
  __syncthreads();
  mfma_128k(sIn, sW, wr, wc, lrow, lk, acc);
  __syncthreads();

  stage_w_async(sW, W0T, 384, 256, tid);
  if (ea_f32) stage_rows_f32(sIn, ea_f32 + (size_t)eRow * DD, row, seg);
  else        stage_rows_bf(sIn, ea_bf + (size_t)eRow * DD, row, seg);
  __syncthreads();
  mfma_128k(sIn, sW, wr, wc, lrow, lk, acc);
  __syncthreads();

  transition_relu(sIn, sBias, 0, wr, wc, lrow, lk, acc);
  stage_w_async(sW, W1T, 128, 0, tid);
  __syncthreads();
  mfma_128k(sIn, sW, wr, wc, lrow, lk, acc);
  __syncthreads();

  transition_relu(sIn, sBias, 128, wr, wc, lrow, lk, acc);
  stage_w_async(sW, W2T, 128, 0, tid);
  __syncthreads();
  mfma_128k(sIn, sW, wr, wc, lrow, lk, acc);
  __syncthreads();

  ln_to_sIn(sIn, sPart, sBias, wr, wc, lrow, lk, acc);
  __syncthreads();

  // epilogue: msg (bf16) + ea residual (bf16); coalesced 16B stores (NO nt hints:
  // 16B/lane access doesn't cover 64B lines per instruction -> nt caused 4x HBM amplification)
  const int e = e0 + row;
  if (e < E) {
    short8 msgv[4];
    #pragma unroll
    for (int j = 0; j < 4; ++j)
      msgv[j] = *(const short8*)((const char*)sIn + swz256(row, seg * 64 + j * 16));
    u16* msgRow = msg_out + (size_t)e * DD + seg * 32;
    u16* eaRow  = ea_bf + (size_t)e * DD + seg * 32;
    if (ea_f32) {
      const float* er = ea_f32 + (size_t)e * DD + seg * 32;
      #pragma unroll
      for (int j = 0; j < 4; ++j) {
        f32x4 o0 = *(const f32x4*)(er + j * 8);
        f32x4 o1 = *(const f32x4*)(er + j * 8 + 4);
        short8 en;
        #pragma unroll
        for (int q = 0; q < 4; ++q) {
          en[q]     = (short)f2bf(o0[q] + bf2f((u16)msgv[j][q]));
          en[4 + q] = (short)f2bf(o1[q] + bf2f((u16)msgv[j][4 + q]));
        }
        *(short8*)(eaRow + j * 8) = en;
        *(short8*)(msgRow + j * 8) = msgv[j];
      }
    } else {
      #pragma unroll
      for (int j = 0; j < 4; ++j) {
        short8 old = *(const short8*)(eaRow + j * 8);
        short8 en;
        #pragma unroll
        for (int q = 0; q < 8; ++q)
          en[q] = (short)f2bf(bf2f((u16)old[q]) + bf2f((u16)msgv[j][q]));
        *(short8*)(eaRow + j * 8) = en;
        *(short8*)(msgRow + j * 8) = msgv[j];
      }
    }
  }
}

__global__ __launch_bounds__(512, 2) void edge_conv_kernel(
    const u16* __restrict__ xm_bf, const u16* __restrict__ xo_bf,
    const int* __restrict__ ei_mm, const int* __restrict__ ei_mo,
    const float* __restrict__ eaf_mm, const float* __restrict__ eaf_mo,
    u16* __restrict__ eab_mm, u16* __restrict__ eab_mo,
    const u16* __restrict__ W0a, const u16* __restrict__ W1a, const u16* __restrict__ W2a,
    const u16* __restrict__ W0b, const u16* __restrict__ W1b, const u16* __restrict__ W2b,
    const float* __restrict__ b0a, const float* __restrict__ b1a, const float* __restrict__ b2a,
    const float* __restrict__ ga, const float* __restrict__ bta,
    const float* __restrict__ b0b, const float* __restrict__ b1b, const float* __restrict__ b2b,
    const float* __restrict__ gb, const float* __restrict__ btb,
    u16* __restrict__ msg_mm, u16* __restrict__ msg_mo)
{
  __shared__ u16 sIn[128 * 128];
  __shared__ u16 sW[128 * 128];
  __shared__ float sBias[5 * 128];
  __shared__ float sPart[2 * 128 * 2];
  if ((int)blockIdx.x < NB_MM)
    edge_body(blockIdx.x, xm_bf, xm_bf, ei_mm, EMMN, eaf_mm, eab_mm,
              W0a, W1a, W2a, b0a, b1a, b2a, ga, bta, msg_mm, sIn, sW, sBias, sPart);
  else
    edge_body(blockIdx.x - NB_MM, xm_bf, xo_bf, ei_mo, EMON, eaf_mo, eab_mo,
              W0b, W1b, W2b, b0b, b1b, b2b, gb, btb, msg_mo, sIn, sW, sBias, sPart);
}

// ---------------- node conv body (128 nodes / block)
static __device__ void node_body(int bid, u16* x_bf, const float* aggin, float* x_f32, int N,
    const u16* W0T, const u16* W1T, const u16* W2T,
    const float* b0, const float* b1, const float* b2,
    const float* gq, const float* btq,
    u16* sIn, u16* sW, float* sBias, float* sPart)
{
  const int tid = threadIdx.x;
  const int wave = tid >> 6, lane = tid & 63;
  const int lrow = lane & 15, lk = lane >> 4;
  const int wr = wave >> 1, wc = wave & 1;
  const int n0 = bid * 128;
  const int row = tid >> 2, seg = tid & 3;
  const int nRow = (n0 + row < N) ? (n0 + row) : (N - 1);

  if (tid < 128) {
    sBias[tid] = b0[tid];
    sBias[128 + tid] = b1[tid];
    sBias[256 + tid] = b2[tid];
    sBias[384 + tid] = gq[tid];
    sBias[512 + tid] = btq[tid];
  }

  const f32x4 zero = {0.f, 0.f, 0.f, 0.f};
  f32x4 acc[2][4];
  #pragma unroll
  for (int i = 0; i < 2; ++i)
    #pragma unroll
    for (int j = 0; j < 4; ++j) acc[i][j] = zero;

  stage_w_async(sW, W0T, 256, 0, tid);
  stage_rows_bf(sIn, x_bf + (size_t)nRow * DD, row, seg);
  __syncthreads();
  mfma_128k(sIn, sW, wr, wc, lrow, lk, acc);
  __syncthreads();

  stage_w_async(sW, W0T, 256, 128, tid);
  stage_rows_f32(sIn, aggin + (size_t)nRow * DD, row, seg);
  __syncthreads();
  mfma_128k(sIn, sW, wr, wc, lrow, lk, acc);
  __syncthreads();

  transition_relu(sIn, sBias, 0, wr, wc, lrow, lk, acc);
  stage_w_async(sW, W1T, 128, 0, tid);
  __syncthreads();
  mfma_128k(sIn, sW, wr, wc, lrow, lk, acc);
  __syncthreads();

  transition_relu(sIn, sBias, 128, wr, wc, lrow, lk, acc);
  stage_w_async(sW, W2T, 128, 0, tid);
  __syncthreads();
  mfma_128k(sIn, sW, wr, wc, lrow, lk, acc);
  __syncthreads();

  ln_to_sIn(sIn, sPart, sBias, wr, wc, lrow, lk, acc);
  __syncthreads();

  // epilogue: x_f32 += ln ; refresh x_bf
  const int n = n0 + row;
  if (n < N) {
    short8 lnv[4];
    #pragma unroll
    for (int j = 0; j < 4; ++j)
      lnv[j] = *(const short8*)((const char*)sIn + swz256(row, seg * 64 + j * 16));
    float* xr = x_f32 + (size_t)n * DD + seg * 32;
    u16* xb = x_bf + (size_t)n * DD + seg * 32;
    #pragma unroll
    for (int j = 0; j < 4; ++j) {
      f32x4 o0 = *(const f32x4*)(xr + j * 8);
      f32x4 o1 = *(const f32x4*)(xr + j * 8 + 4);
      f32x4 n0v, n1v;
      short8 pb;
      #pragma unroll
      for (int q = 0; q < 4; ++q) {
        n0v[q] = o0[q] + bf2f((u16)lnv[j][q]);
        n1v[q] = o1[q] + bf2f((u16)lnv[j][4 + q]);
        pb[q]     = (short)f2bf(n0v[q]);
        pb[4 + q] = (short)f2bf(n1v[q]);
      }
      *(f32x4*)(xr + j * 8) = n0v;
      *(f32x4*)(xr + j * 8 + 4) = n1v;
      *(short8*)(xb + j * 8) = pb;
    }
  }
}

__global__ __launch_bounds__(512, 2) void node_conv_kernel(
    u16* __restrict__ xm_bf, u16* __restrict__ xo_bf,
    const float* __restrict__ agg_m, const float* __restrict__ agg_o,
    float* __restrict__ xf_m, float* __restrict__ xf_o,
    const u16* __restrict__ W0a, const u16* __restrict__ W1a, const u16* __restrict__ W2a,
    const u16* __restrict__ W0b, const u16* __restrict__ W1b, const u16* __restrict__ W2b,
    const float* __restrict__ b0a, const float* __restrict__ b1a, const float* __restrict__ b2a,
    const float* __restrict__ ga, const float* __restrict__ bta,
    const float* __restrict__ b0b, const float* __restrict__ b1b, const float* __restrict__ b2b,
    const float* __restrict__ gb, const float* __restrict__ btb)
{
  __shared__ u16 sIn[128 * 128];
  __shared__ u16 sW[128 * 128];
  __shared__ float sBias[5 * 128];
  __shared__ float sPart[2 * 128 * 2];
  if ((int)blockIdx.x < NB_NM)
    node_body(blockIdx.x, xm_bf, agg_m, xf_m, NMESH,
              W0a, W1a, W2a, b0a, b1a, b2a, ga, bta, sIn, sW, sBias, sPart);
  else
    node_body(blockIdx.x - NB_NM, xo_bf, agg_o, xf_o, NOBJ,
              W0b, W1b, W2b, b0b, b1b, b2b, gb, btb, sIn, sW, sBias, sPart);
}

// ---------------- CSR build ----------------
__global__ void hist_kernel(const int* __restrict__ ei_mm, const int* __restrict__ ei_mo,
                            int* __restrict__ deg_m, int* __restrict__ deg_o) {
  int i = blockIdx.x * blockDim.x + threadIdx.x;
  if (i < EMMN) atomicAdd(&deg_m[ei_mm[EMMN + i]], 1);
  else { int j = i - EMMN; if (j < EMON) atomicAdd(&deg_o[ei_mo[EMON + j]], 1); }
}

__global__ __launch_bounds__(1024) void scan_kernel(
    const int* __restrict__ deg_m, int* __restrict__ start_m, int* __restrict__ cur_m,
    const int* __restrict__ deg_o, int* __restrict__ start_o, int* __restrict__ cur_o) {
  const int* deg; int* start; int* cursor; int N;
  if (blockIdx.x == 0) { deg = deg_m; start = start_m; cursor = cur_m; N = NMESH; }
  else                 { deg = deg_o; start = start_o; cursor = cur_o; N = NOBJ; }
  __shared__ int lds[1024];
  const int t = threadIdx.x;
  const int chunk = (N + 1023) >> 10;
  const int base = t * chunk;
  const int end = min(base + chunk, N);
  int s = 0;
  for (int i = base; i < end; ++i) s += deg[i];
  lds[t] = s;
  __syncthreads();
  for (int d = 1; d < 1024; d <<= 1) {
    int v = (t >= d) ? lds[t - d] : 0;
    __syncthreads();
    lds[t] += v;
    __syncthreads();
  }
  int off = lds[t] - s;
  for (int i = base; i < end; ++i) { start[i] = off; cursor[i] = off; off += deg[i]; }
  if (t == 1023) start[N] = lds[1023];
}

__global__ void scatter_kernel(const int* __restrict__ ei_mm, const int* __restrict__ ei_mo,
                               int* __restrict__ cur_m, int* __restrict__ cur_o,
                               int* __restrict__ perm_m, int* __restrict__ perm_o) {
  int i = blockIdx.x * blockDim.x + threadIdx.x;
  if (i < EMMN) { int p = atomicAdd(&cur_m[ei_mm[EMMN + i]], 1); perm_m[p] = i; }
  else { int j = i - EMMN; if (j < EMON) { int p = atomicAdd(&cur_o[ei_mo[EMON + j]], 1); perm_o[p] = j; } }
}

// ---------------- aggregate (CSR gather), mesh+obj merged
__global__ __launch_bounds__(256) void agg_gather_kernel(
    const u16* __restrict__ msg_m, const int* __restrict__ start_m, const int* __restrict__ perm_m,
    float* __restrict__ agg_m,
    const u16* __restrict__ msg_o, const int* __restrict__ start_o, const int* __restrict__ perm_o,
    float* __restrict__ agg_o)
{
  const int wave = threadIdx.x >> 6, lane = threadIdx.x & 63;
  int idx = blockIdx.x * 4 + wave;
  const u16* msg; const int* start; const int* perm; float* agg; int n;
  if (idx < NMESH) { msg = msg_m; start = start_m; perm = perm_m; agg = agg_m; n = idx; }
  else {
    n = idx - NMESH;
    if (n >= NOBJ) return;
    msg = msg_o; start = start_o; perm = perm_o; agg = agg_o;
  }
  const int i0 = start[n], i1 = start[n + 1];
  float a0 = 0.f, a1 = 0.f;
  int i = i0;
  for (; i + 1 < i1; i += 2) {
    const int e1 = perm[i], e2 = perm[i + 1];
    unsigned v1 = *(const unsigned*)(msg + (size_t)e1 * DD + lane * 2);
    unsigned v2 = *(const unsigned*)(msg + (size_t)e2 * DD + lane * 2);
    a0 += bf2f((u16)(v1 & 0xFFFFu)) + bf2f((u16)(v2 & 0xFFFFu));
    a1 += bf2f((u16)(v1 >> 16)) + bf2f((u16)(v2 >> 16));
  }
  if (i < i1) {
    const int e1 = perm[i];
    unsigned v1 = *(const unsigned*)(msg + (size_t)e1 * DD + lane * 2);
    a0 += bf2f((u16)(v1 & 0xFFFFu));
    a1 += bf2f((u16)(v1 >> 16));
  }
  float* ar = agg + (size_t)n * DD + lane * 2;
  ar[0] = a0;
  ar[1] = a1;
}

// ---------------- one merged prep kernel ----------------
static __device__ __forceinline__ void wcvt(const float* src, u16* dst, int K, int b, int t) {
  int i = b * 256 + t;
  int n = i & 127;
  int k = (i >> 7) % K;
  int sl = i / (K * 128);
  dst[((size_t)sl * 128 + n) * K + k] = f2bf(src[i]);
}

__global__ void prep_kernel(
    const float* __restrict__ eW0, const float* __restrict__ eW1, const float* __restrict__ eW2,
    const float* __restrict__ nW0, const float* __restrict__ nW1, const float* __restrict__ nW2,
    u16* __restrict__ eW0T, u16* __restrict__ eW1T, u16* __restrict__ eW2T,
    u16* __restrict__ nW0T, u16* __restrict__ nW1T, u16* __restrict__ nW2T,
    int* __restrict__ deg_m, int* __restrict__ deg_o,
    const float* __restrict__ xm, const float* __restrict__ xo,
    float* __restrict__ xf, u16* __restrict__ xmb, u16* __restrict__ xob)
{
  const int b = blockIdx.x, t = threadIdx.x;
  if (b < 768)        wcvt(eW0, eW0T, 384, b, t);
  else if (b < 1024)  wcvt(eW1, eW1T, 128, b - 768, t);
  else if (b < 1280)  wcvt(eW2, eW2T, 128, b - 1024, t);
  else if (b < 1792)  wcvt(nW0, nW0T, 256, b - 1280, t);
  else if (b < 2048)  wcvt(nW1, nW1T, 128, b - 1792, t);
  else if (b < 2304)  wcvt(nW2, nW2T, 128, b - 2048, t);
  else if (b < 2429) {
    int i = (b - 2304) * 256 + t;
    if (i < NMESH) deg_m[i] = 0;
    else if (i < NMESH + NOBJ) deg_o[i - NMESH] = 0;
  } else {
    int i = (b - 2429) * 256 + t;
    const int tm = NMESH * DD;
    if (i < tm) { float v = xm[i]; xf[i] = v; xmb[i] = f2bf(v); }
    else { int j = i - tm; float v = xo[j]; xf[tm + j] = v; xob[j] = f2bf(v); }
  }
}

extern "C" void kernel_launch(void* const* d_in, const int* in_sizes, int n_in,
                              void* d_out, int out_size, void* d_ws, size_t ws_size,
                              hipStream_t stream)
{
  const float* x_mesh = (const float*)d_in[0];
  const float* x_obj  = (const float*)d_in[1];
  const int*   ei_mm  = (const int*)d_in[2];
  const int*   ei_mo  = (const int*)d_in[3];
  const float* ea_mm  = (const float*)d_in[4];
  const float* ea_mo  = (const float*)d_in[5];
  const float* eW0 = (const float*)d_in[6];
  const float* eb0 = (const float*)d_in[7];
  const float* eW1 = (const float*)d_in[8];
  const float* eb1 = (const float*)d_in[9];
  const float* eW2 = (const float*)d_in[10];
  const float* eb2 = (const float*)d_in[11];
  const float* eg  = (const float*)d_in[12];
  const float* ebt = (const float*)d_in[13];
  const float* nW0 = (const float*)d_in[14];
  const float* nb0 = (const float*)d_in[15];
  const float* nW1 = (const float*)d_in[16];
  const float* nb1 = (const float*)d_in[17];
  const float* nW2 = (const float*)d_in[18];
  const float* nb2 = (const float*)d_in[19];
  const float* ng  = (const float*)d_in[20];
  const float* nbt = (const float*)d_in[21];

  u16* eamm_bf = (u16*)d_ws;
  u16* eamo_bf = eamm_bf + (size_t)EMMN * DD;
  u16* xm_bf   = eamo_bf + (size_t)EMON * DD;
  u16* xo_bf   = xm_bf + (size_t)NMESH * DD;
  float* agg_m = (float*)(xo_bf + (size_t)NOBJ * DD);
  float* agg_o = agg_m + (size_t)NMESH * DD;
  u16* eW0T = (u16*)(agg_o + (size_t)NOBJ * DD);
  u16* eW1T = eW0T + (size_t)4 * 128 * 384;
  u16* eW2T = eW1T + (size_t)4 * 128 * 128;
  u16* nW0T = eW2T + (size_t)4 * 128 * 128;
  u16* nW1T = nW0T + (size_t)4 * 128 * 256;
  u16* nW2T = nW1T + (size_t)4 * 128 * 128;
  u16* msg_mm = nW2T + (size_t)4 * 128 * 128;
  u16* msg_mo = msg_mm + (size_t)EMMN * DD;
  int* deg_m   = (int*)(msg_mo + (size_t)EMON * DD);
  int* start_m = deg_m + NMESH;
  int* cur_m   = start_m + NMESH + 1;
  int* perm_mm = cur_m + NMESH;
  int* deg_o   = perm_mm + EMMN;
  int* start_o = deg_o + NOBJ;
  int* cur_o   = start_o + NOBJ + 1;
  int* perm_mo = cur_o + NOBJ;

  float* xf_m = (float*)d_out;
  float* xf_o = xf_m + (size_t)NMESH * DD;

  prep_kernel<<<18429, 256, 0, stream>>>(eW0, eW1, eW2, nW0, nW1, nW2,
                                         eW0T, eW1T, eW2T, nW0T, nW1T, nW2T,
                                         deg_m, deg_o, x_mesh, x_obj, xf_m, xm_bf, xo_bf);
  hist_kernel<<<(EMMN + EMON + 255) / 256, 256, 0, stream>>>(ei_mm, ei_mo, deg_m, deg_o);
  scan_kernel<<<2, 1024, 0, stream>>>(deg_m, start_m, cur_m, deg_o, start_o, cur_o);
  scatter_kernel<<<(EMMN + EMON + 255) / 256, 256, 0, stream>>>(ei_mm, ei_mo, cur_m, cur_o,
                                                                perm_mm, perm_mo);

  for (int s = 0; s < 2; ++s) {
    const int sa = 0 * 2 + s, sb = 1 * 2 + s;
    edge_conv_kernel<<<NB_MM + NB_MO, 512, 0, stream>>>(
        xm_bf, xo_bf, ei_mm, ei_mo,
        (s == 0) ? ea_mm : (const float*)nullptr,
        (s == 0) ? ea_mo : (const float*)nullptr,
        eamm_bf, eamo_bf,
        eW0T + (size_t)sa * 128 * 384, eW1T + (size_t)sa * 128 * 128, eW2T + (size_t)sa * 128 * 128,
        eW0T + (size_t)sb * 128 * 384, eW1T + (size_t)sb * 128 * 128, eW2T + (size_t)sb * 128 * 128,
        eb0 + sa * 128, eb1 + sa * 128, eb2 + sa * 128, eg + sa * 128, ebt + sa * 128,
        eb0 + sb * 128, eb1 + sb * 128, eb2 + sb * 128, eg + sb * 128, ebt + sb * 128,
        msg_mm, msg_mo);
    agg_gather_kernel<<<(NMESH + NOBJ + 3) / 4, 256, 0, stream>>>(
        msg_mm, start_m, perm_mm, agg_m, msg_mo, start_o, perm_mo, agg_o);
    node_conv_kernel<<<NB_NM + NB_NO, 512, 0, stream>>>(
        xm_bf, xo_bf, agg_m, agg_o, xf_m, xf_o,
        nW0T + (size_t)sa * 128 * 256, nW1T + (size_t)sa * 128 * 128, nW2T + (size_t)sa * 128 * 128,
        nW0T + (size_t)sb * 128 * 256, nW1T + (size_t)sb * 128 * 128, nW2T + (size_t)sb * 128 * 128,
        nb0 + sa * 128, nb1 + sa * 128, nb2 + sa * 128, ng + sa * 128, nbt + sa * 128,
        nb0 + sb * 128, nb1 + sb * 128, nb2 + sb * 128, ng + sb * 128, nbt + sb * 128);
  }
}

// Round 7
// 739.865 us; speedup vs baseline: 1.3937x; 1.0082x over previous
//
#include <hip/hip_runtime.h>

#define DD 128
#define NMESH 30000
#define NOBJ 2000
#define EMMN 240000
#define EMON 60000
#define NB_MM (EMMN / 128)           // 1875
#define NB_MO ((EMON + 127) / 128)   // 469
#define NB_NM ((NMESH + 127) / 128)  // 235
#define NB_NO ((NOBJ + 127) / 128)   // 16

typedef unsigned short u16;
typedef short short8 __attribute__((ext_vector_type(8)));
typedef float f32x4 __attribute__((ext_vector_type(4)));
typedef __bf16 bf16x8 __attribute__((ext_vector_type(8)));

union FragCvt { short8 s; bf16x8 b; };

static __device__ __forceinline__ u16 f2bf(float f) {
  union { float f; unsigned u; } v; v.f = f;
  unsigned r = v.u + 0x7FFFu + ((v.u >> 16) & 1u);
  return (u16)(r >> 16);
}
static __device__ __forceinline__ float bf2f(u16 u) {
  union { unsigned u; float f; } v; v.u = ((unsigned)u) << 16; return v.f;
}
// swizzle: XOR 16B-chunk index with row&7 (byte bits 4..6) -> conflict-free ds_read_b128
static __device__ __forceinline__ int swz256(int row, int b) {
  return row * 256 + (b ^ ((row & 7) << 4));
}
static __device__ __forceinline__ bf16x8 ldsFrag(const u16* s, int row, int kByte) {
  FragCvt u; u.s = *(const short8*)((const char*)s + swz256(row, kByte));
  return u.b;
}

// stage a 128x128 bf16 weight block: global (L2-cached!) -> VGPR -> swizzled ds_write.
// NOT global_load_lds: that path streams past L2, and weights are reused by
// ~2300 blocks -> must be served from L2/L3 (R6 counter evidence: +200MB HBM fetch).
static __device__ __forceinline__ void stage_w(u16* sW, const u16* W,
                                               int rowLen, int colOff, int tid) {
  const int row = tid >> 2;      // 128 rows, 4 threads/row
  const int half = tid & 3;      // 32 cols (64B) each
  const u16* g = W + (size_t)row * rowLen + colOff + half * 32;
  short8 v0 = *(const short8*)(g);
  short8 v1 = *(const short8*)(g + 8);
  short8 v2 = *(const short8*)(g + 16);
  short8 v3 = *(const short8*)(g + 24);
  *(short8*)((char*)sW + swz256(row, half * 64)) = v0;
  *(short8*)((char*)sW + swz256(row, half * 64 + 16)) = v1;
  *(short8*)((char*)sW + swz256(row, half * 64 + 32)) = v2;
  *(short8*)((char*)sW + swz256(row, half * 64 + 48)) = v3;
}

// one K=128 GEMM part: per wave 32 rows x 64 cols
static __device__ __forceinline__ void mfma_128k(const u16* sIn, const u16* sW,
                                                 int wr, int wc, int lrow, int lk,
                                                 f32x4 acc[2][4]) {
  #pragma unroll
  for (int kc = 0; kc < 4; ++kc) {
    bf16x8 a0 = ldsFrag(sIn, wr * 32 + lrow, kc * 64 + lk * 16);
    bf16x8 a1 = ldsFrag(sIn, wr * 32 + 16 + lrow, kc * 64 + lk * 16);
    #pragma unroll
    for (int ct = 0; ct < 4; ++ct) {
      bf16x8 b = ldsFrag(sW, wc * 64 + ct * 16 + lrow, kc * 64 + lk * 16);
      acc[0][ct] = __builtin_amdgcn_mfma_f32_16x16x32_bf16(a0, b, acc[0][ct], 0, 0, 0);
      acc[1][ct] = __builtin_amdgcn_mfma_f32_16x16x32_bf16(a1, b, acc[1][ct], 0, 0, 0);
    }
  }
}

static __device__ __forceinline__ void transition_relu(u16* sIn, const float* sBias, int biasOff,
                                                       int wr, int wc, int lrow, int lk,
                                                       f32x4 acc[2][4]) {
  #pragma unroll
  for (int rt = 0; rt < 2; ++rt) {
    #pragma unroll
    for (int ct = 0; ct < 4; ++ct) {
      const int col = wc * 64 + ct * 16 + lrow;
      const float bias = sBias[biasOff + col];
      #pragma unroll
      for (int r = 0; r < 4; ++r) {
        const int orow = wr * 32 + rt * 16 + lk * 4 + r;
        float v = acc[rt][ct][r] + bias;
        v = fmaxf(v, 0.f);
        *(u16*)((char*)sIn + swz256(orow, col * 2)) = f2bf(v);
        acc[rt][ct][r] = 0.f;
      }
    }
  }
}

// in-register LayerNorm from accumulators; result (bf16) staged into sIn.
// contains one __syncthreads (uniform).
static __device__ __forceinline__ void ln_to_sIn(u16* sIn, float* sPart, const float* sBias,
                                                 int wr, int wc, int lrow, int lk,
                                                 f32x4 acc[2][4]) {
  float gv[4], bv[4];
  #pragma unroll
  for (int ct = 0; ct < 4; ++ct) {
    const int col = wc * 64 + ct * 16 + lrow;
    gv[ct] = sBias[384 + col];
    bv[ct] = sBias[512 + col];
  }
  float s1[2][4], s2[2][4];
  #pragma unroll
  for (int rt = 0; rt < 2; ++rt) {
    #pragma unroll
    for (int r = 0; r < 4; ++r) {
      float a = 0.f, b = 0.f;
      #pragma unroll
      for (int ct = 0; ct < 4; ++ct) {
        const int col = wc * 64 + ct * 16 + lrow;
        const float v = acc[rt][ct][r] + sBias[256 + col];  // + b2
        acc[rt][ct][r] = v;
        a += v; b += v * v;
      }
      #pragma unroll
      for (int m = 1; m < 16; m <<= 1) { a += __shfl_xor(a, m); b += __shfl_xor(b, m); }
      s1[rt][r] = a; s2[rt][r] = b;   // wc-half sums, same edge across the 16-lane group
    }
  }
  if (lrow == 0) {
    #pragma unroll
    for (int rt = 0; rt < 2; ++rt)
      #pragma unroll
      for (int r = 0; r < 4; ++r) {
        const int e = wr * 32 + rt * 16 + lk * 4 + r;
        sPart[(wc * 128 + e) * 2] = s1[rt][r];
        sPart[(wc * 128 + e) * 2 + 1] = s2[rt][r];
      }
  }
  __syncthreads();
  #pragma unroll
  for (int rt = 0; rt < 2; ++rt)
    #pragma unroll
    for (int r = 0; r < 4; ++r) {
      const int e = wr * 32 + rt * 16 + lk * 4 + r;
      const float t1 = s1[rt][r] + sPart[((1 - wc) * 128 + e) * 2];
      const float t2 = s2[rt][r] + sPart[((1 - wc) * 128 + e) * 2 + 1];
      const float m = t1 * (1.f / 128.f);
      const float var = t2 * (1.f / 128.f) - m * m;
      const float rstd = rsqrtf(var + 1e-5f);
      #pragma unroll
      for (int ct = 0; ct < 4; ++ct) {
        const int col = wc * 64 + ct * 16 + lrow;
        const float ln = (acc[rt][ct][r] - m) * rstd * gv[ct] + bv[ct];
        *(u16*)((char*)sIn + swz256(e, col * 2)) = f2bf(ln);
      }
    }
}

static __device__ __forceinline__ void stage_rows_bf(u16* sIn, const u16* src, int row, int seg) {
  #pragma unroll
  for (int j = 0; j < 4; ++j) {
    short8 v = *(const short8*)(src + seg * 32 + j * 8);
    *(short8*)((char*)sIn + swz256(row, seg * 64 + j * 16)) = v;
  }
}
static __device__ __forceinline__ void stage_rows_f32(u16* sIn, const float* src, int row, int seg) {
  #pragma unroll
  for (int j = 0; j < 4; ++j) {
    const int c0 = seg * 32 + j * 8;
    f32x4 f0 = *(const f32x4*)(src + c0);
    f32x4 f1 = *(const f32x4*)(src + c0 + 4);
    short8 v;
    #pragma unroll
    for (int q = 0; q < 4; ++q) { v[q] = (short)f2bf(f0[q]); v[4 + q] = (short)f2bf(f1[q]); }
    *(short8*)((char*)sIn + swz256(row, seg * 64 + j * 16)) = v;
  }
}

// ---------------- edge conv body (128 edges / block, 8 waves)
static __device__ void edge_body(int bid,
    const u16* xsrc, const u16* xdst, const int* ei, int E,
    const float* ea_f32, u16* ea_bf,
    const u16* W0T, const u16* W1T, const u16* W2T,
    const float* b0, const float* b1, const float* b2,
    const float* gq, const float* btq, u16* msg_out,
    u16* sIn, u16* sW, float* sBias, float* sPart)
{
  const int tid = threadIdx.x;
  const int wave = tid >> 6, lane = tid & 63;
  const int lrow = lane & 15, lk = lane >> 4;
  const int wr = wave >> 1, wc = wave & 1;
  const int e0 = bid * 128;
  const int row = tid >> 2, seg = tid & 3;
  const int eRow = (e0 + row < E) ? (e0 + row) : (E - 1);

  if (tid < 128) {
    sBias[tid] = b0[tid];
    sBias[128 + tid] = b1[tid];
    sBias[256 + tid] = b2[tid];
    sBias[384 + tid] = gq[tid];
    sBias[512 + tid] = btq[tid];
  }

  const f32x4 zero = {0.f, 0.f, 0.f, 0.f};
  f32x4 acc[2][4];
  #pragma unroll
  for (int i = 0; i < 2; ++i)
    #pragma unroll
    for (int j = 0; j < 4; ++j) acc[i][j] = zero;

  // layer 1: three K=128 parts (x_dst, x_src, ea)
  stage_w(sW, W0T, 384, 0, tid);
  { const int idx = ei[E + eRow]; stage_rows_bf(sIn, xdst + (size_t)idx * DD, row, seg); }
  __syncthreads();
  mfma_128k(sIn, sW, wr, wc, lrow, lk, acc);
  __syncthreads();

  stage_w(sW, W0T, 384, 128, tid);
  { const int idx = ei[eRow]; stage_rows_bf(sIn, xsrc + (size_t)idx * DD, row, seg); }
  __syncthreads();
  mfma_128k(sIn, sW, wr, wc, lrow, lk, acc);
  __syncthreads();

  stage_w(sW, W0T, 384, 256, tid);
  if (ea_f32) stage_rows_f32(sIn, ea_f32 + (size_t)eRow * DD, row, seg);
  else        stage_rows_bf(sIn, ea_bf + (size_t)eRow * DD, row, seg);
  __syncthreads();
  mfma_128k(sIn, sW, wr, wc, lrow, lk, acc);
  __syncthreads();

  transition_relu(sIn, sBias, 0, wr, wc, lrow, lk, acc);
  stage_w(sW, W1T, 128, 0, tid);
  __syncthreads();
  mfma_128k(sIn, sW, wr, wc, lrow, lk, acc);
  __syncthreads();

  transition_relu(sIn, sBias, 128, wr, wc, lrow, lk, acc);
  stage_w(sW, W2T, 128, 0, tid);
  __syncthreads();
  mfma_128k(sIn, sW, wr, wc, lrow, lk, acc);
  __syncthreads();

  ln_to_sIn(sIn, sPart, sBias, wr, wc, lrow, lk, acc);
  __syncthreads();

  // epilogue: msg (bf16) + ea residual (bf16); coalesced, each thread owns a
  // contiguous 64B block. Plain stores (nt caused 4x HBM amplification in R5).
  const int e = e0 + row;
  if (e < E) {
    short8 msgv[4];
    #pragma unroll
    for (int j = 0; j < 4; ++j)
      msgv[j] = *(const short8*)((const char*)sIn + swz256(row, seg * 64 + j * 16));
    u16* msgRow = msg_out + (size_t)e * DD + seg * 32;
    u16* eaRow  = ea_bf + (size_t)e * DD + seg * 32;
    if (ea_f32) {
      const float* er = ea_f32 + (size_t)e * DD + seg * 32;
      #pragma unroll
      for (int j = 0; j < 4; ++j) {
        f32x4 o0 = *(const f32x4*)(er + j * 8);
        f32x4 o1 = *(const f32x4*)(er + j * 8 + 4);
        short8 en;
        #pragma unroll
        for (int q = 0; q < 4; ++q) {
          en[q]     = (short)f2bf(o0[q] + bf2f((u16)msgv[j][q]));
          en[4 + q] = (short)f2bf(o1[q] + bf2f((u16)msgv[j][4 + q]));
        }
        *(short8*)(eaRow + j * 8) = en;
        *(short8*)(msgRow + j * 8) = msgv[j];
      }
    } else {
      #pragma unroll
      for (int j = 0; j < 4; ++j) {
        short8 old = *(const short8*)(eaRow + j * 8);
        short8 en;
        #pragma unroll
        for (int q = 0; q < 8; ++q)
          en[q] = (short)f2bf(bf2f((u16)old[q]) + bf2f((u16)msgv[j][q]));
        *(short8*)(eaRow + j * 8) = en;
        *(short8*)(msgRow + j * 8) = msgv[j];
      }
    }
  }
}

__global__ __launch_bounds__(512, 2) void edge_conv_kernel(
    const u16* __restrict__ xm_bf, const u16* __restrict__ xo_bf,
    const int* __restrict__ ei_mm, const int* __restrict__ ei_mo,
    const float* __restrict__ eaf_mm, const float* __restrict__ eaf_mo,
    u16* __restrict__ eab_mm, u16* __restrict__ eab_mo,
    const u16* __restrict__ W0a, const u16* __restrict__ W1a, const u16* __restrict__ W2a,
    const u16* __restrict__ W0b, const u16* __restrict__ W1b, const u16* __restrict__ W2b,
    const float* __restrict__ b0a, const float* __restrict__ b1a, const float* __restrict__ b2a,
    const float* __restrict__ ga, const float* __restrict__ bta,
    const float* __restrict__ b0b, const float* __restrict__ b1b, const float* __restrict__ b2b,
    const float* __restrict__ gb, const float* __restrict__ btb,
    u16* __restrict__ msg_mm, u16* __restrict__ msg_mo)
{
  __shared__ u16 sIn[128 * 128];
  __shared__ u16 sW[128 * 128];
  __shared__ float sBias[5 * 128];
  __shared__ float sPart[2 * 128 * 2];
  if ((int)blockIdx.x < NB_MM)
    edge_body(blockIdx.x, xm_bf, xm_bf, ei_mm, EMMN, eaf_mm, eab_mm,
              W0a, W1a, W2a, b0a, b1a, b2a, ga, bta, msg_mm, sIn, sW, sBias, sPart);
  else
    edge_body(blockIdx.x - NB_MM, xm_bf, xo_bf, ei_mo, EMON, eaf_mo, eab_mo,
              W0b, W1b, W2b, b0b, b1b, b2b, gb, btb, msg_mo, sIn, sW, sBias, sPart);
}

// ---------------- node conv body (128 nodes / block)
static __device__ void node_body(int bid, u16* x_bf, const float* aggin, float* x_f32, int N,
    const u16* W0T, const u16* W1T, const u16* W2T,
    const float* b0, const float* b1, const float* b2,
    const float* gq, const float* btq,
    u16* sIn, u16* sW, float* sBias, float* sPart)
{
  const int tid = threadIdx.x;
  const int wave = tid >> 6, lane = tid & 63;
  const int lrow = lane & 15, lk = lane >> 4;
  const int wr = wave >> 1, wc = wave & 1;
  const int n0 = bid * 128;
  const int row = tid >> 2, seg = tid & 3;
  const int nRow = (n0 + row < N) ? (n0 + row) : (N - 1);

  if (tid < 128) {
    sBias[tid] = b0[tid];
    sBias[128 + tid] = b1[tid];
    sBias[256 + tid] = b2[tid];
    sBias[384 + tid] = gq[tid];
    sBias[512 + tid] = btq[tid];
  }

  const f32x4 zero = {0.f, 0.f, 0.f, 0.f};
  f32x4 acc[2][4];
  #pragma unroll
  for (int i = 0; i < 2; ++i)
    #pragma unroll
    for (int j = 0; j < 4; ++j) acc[i][j] = zero;

  stage_w(sW, W0T, 256, 0, tid);
  stage_rows_bf(sIn, x_bf + (size_t)nRow * DD, row, seg);
  __syncthreads();
  mfma_128k(sIn, sW, wr, wc, lrow, lk, acc);
  __syncthreads();

  stage_w(sW, W0T, 256, 128, tid);
  stage_rows_f32(sIn, aggin + (size_t)nRow * DD, row, seg);
  __syncthreads();
  mfma_128k(sIn, sW, wr, wc, lrow, lk, acc);
  __syncthreads();

  transition_relu(sIn, sBias, 0, wr, wc, lrow, lk, acc);
  stage_w(sW, W1T, 128, 0, tid);
  __syncthreads();
  mfma_128k(sIn, sW, wr, wc, lrow, lk, acc);
  __syncthreads();

  transition_relu(sIn, sBias, 128, wr, wc, lrow, lk, acc);
  stage_w(sW, W2T, 128, 0, tid);
  __syncthreads();
  mfma_128k(sIn, sW, wr, wc, lrow, lk, acc);
  __syncthreads();

  ln_to_sIn(sIn, sPart, sBias, wr, wc, lrow, lk, acc);
  __syncthreads();

  // epilogue: x_f32 += ln ; refresh x_bf
  const int n = n0 + row;
  if (n < N) {
    short8 lnv[4];
    #pragma unroll
    for (int j = 0; j < 4; ++j)
      lnv[j] = *(const short8*)((const char*)sIn + swz256(row, seg * 64 + j * 16));
    float* xr = x_f32 + (size_t)n * DD + seg * 32;
    u16* xb = x_bf + (size_t)n * DD + seg * 32;
    #pragma unroll
    for (int j = 0; j < 4; ++j) {
      f32x4 o0 = *(const f32x4*)(xr + j * 8);
      f32x4 o1 = *(const f32x4*)(xr + j * 8 + 4);
      f32x4 n0v, n1v;
      short8 pb;
      #pragma unroll
      for (int q = 0; q < 4; ++q) {
        n0v[q] = o0[q] + bf2f((u16)lnv[j][q]);
        n1v[q] = o1[q] + bf2f((u16)lnv[j][4 + q]);
        pb[q]     = (short)f2bf(n0v[q]);
        pb[4 + q] = (short)f2bf(n1v[q]);
      }
      *(f32x4*)(xr + j * 8) = n0v;
      *(f32x4*)(xr + j * 8 + 4) = n1v;
      *(short8*)(xb + j * 8) = pb;
    }
  }
}

__global__ __launch_bounds__(512, 2) void node_conv_kernel(
    u16* __restrict__ xm_bf, u16* __restrict__ xo_bf,
    const float* __restrict__ agg_m, const float* __restrict__ agg_o,
    float* __restrict__ xf_m, float* __restrict__ xf_o,
    const u16* __restrict__ W0a, const u16* __restrict__ W1a, const u16* __restrict__ W2a,
    const u16* __restrict__ W0b, const u16* __restrict__ W1b, const u16* __restrict__ W2b,
    const float* __restrict__ b0a, const float* __restrict__ b1a, const float* __restrict__ b2a,
    const float* __restrict__ ga, const float* __restrict__ bta,
    const float* __restrict__ b0b, const float* __restrict__ b1b, const float* __restrict__ b2b,
    const float* __restrict__ gb, const float* __restrict__ btb)
{
  __shared__ u16 sIn[128 * 128];
  __shared__ u16 sW[128 * 128];
  __shared__ float sBias[5 * 128];
  __shared__ float sPart[2 * 128 * 2];
  if ((int)blockIdx.x < NB_NM)
    node_body(blockIdx.x, xm_bf, agg_m, xf_m, NMESH,
              W0a, W1a, W2a, b0a, b1a, b2a, ga, bta, sIn, sW, sBias, sPart);
  else
    node_body(blockIdx.x - NB_NM, xo_bf, agg_o, xf_o, NOBJ,
              W0b, W1b, W2b, b0b, b1b, b2b, gb, btb, sIn, sW, sBias, sPart);
}

// ---------------- CSR build ----------------
__global__ void hist_kernel(const int* __restrict__ ei_mm, const int* __restrict__ ei_mo,
                            int* __restrict__ deg_m, int* __restrict__ deg_o) {
  int i = blockIdx.x * blockDim.x + threadIdx.x;
  if (i < EMMN) atomicAdd(&deg_m[ei_mm[EMMN + i]], 1);
  else { int j = i - EMMN; if (j < EMON) atomicAdd(&deg_o[ei_mo[EMON + j]], 1); }
}

__global__ __launch_bounds__(1024) void scan_kernel(
    const int* __restrict__ deg_m, int* __restrict__ start_m, int* __restrict__ cur_m,
    const int* __restrict__ deg_o, int* __restrict__ start_o, int* __restrict__ cur_o) {
  const int* deg; int* start; int* cursor; int N;
  if (blockIdx.x == 0) { deg = deg_m; start = start_m; cursor = cur_m; N = NMESH; }
  else                 { deg = deg_o; start = start_o; cursor = cur_o; N = NOBJ; }
  __shared__ int lds[1024];
  const int t = threadIdx.x;
  const int chunk = (N + 1023) >> 10;
  const int base = t * chunk;
  const int end = min(base + chunk, N);
  int s = 0;
  for (int i = base; i < end; ++i) s += deg[i];
  lds[t] = s;
  __syncthreads();
  for (int d = 1; d < 1024; d <<= 1) {
    int v = (t >= d) ? lds[t - d] : 0;
    __syncthreads();
    lds[t] += v;
    __syncthreads();
  }
  int off = lds[t] - s;
  for (int i = base; i < end; ++i) { start[i] = off; cursor[i] = off; off += deg[i]; }
  if (t == 1023) start[N] = lds[1023];
}

__global__ void scatter_kernel(const int* __restrict__ ei_mm, const int* __restrict__ ei_mo,
                               int* __restrict__ cur_m, int* __restrict__ cur_o,
                               int* __restrict__ perm_m, int* __restrict__ perm_o) {
  int i = blockIdx.x * blockDim.x + threadIdx.x;
  if (i < EMMN) { int p = atomicAdd(&cur_m[ei_mm[EMMN + i]], 1); perm_m[p] = i; }
  else { int j = i - EMMN; if (j < EMON) { int p = atomicAdd(&cur_o[ei_mo[EMON + j]], 1); perm_o[p] = j; } }
}

// ---------------- aggregate (CSR gather), mesh+obj merged
__global__ __launch_bounds__(256) void agg_gather_kernel(
    const u16* __restrict__ msg_m, const int* __restrict__ start_m, const int* __restrict__ perm_m,
    float* __restrict__ agg_m,
    const u16* __restrict__ msg_o, const int* __restrict__ start_o, const int* __restrict__ perm_o,
    float* __restrict__ agg_o)
{
  const int wave = threadIdx.x >> 6, lane = threadIdx.x & 63;
  int idx = blockIdx.x * 4 + wave;
  const u16* msg; const int* start; const int* perm; float* agg; int n;
  if (idx < NMESH) { msg = msg_m; start = start_m; perm = perm_m; agg = agg_m; n = idx; }
  else {
    n = idx - NMESH;
    if (n >= NOBJ) return;
    msg = msg_o; start = start_o; perm = perm_o; agg = agg_o;
  }
  const int i0 = start[n], i1 = start[n + 1];
  float a0 = 0.f, a1 = 0.f;
  int i = i0;
  for (; i + 1 < i1; i += 2) {
    const int e1 = perm[i], e2 = perm[i + 1];
    unsigned v1 = *(const unsigned*)(msg + (size_t)e1 * DD + lane * 2);
    unsigned v2 = *(const unsigned*)(msg + (size_t)e2 * DD + lane * 2);
    a0 += bf2f((u16)(v1 & 0xFFFFu)) + bf2f((u16)(v2 & 0xFFFFu));
    a1 += bf2f((u16)(v1 >> 16)) + bf2f((u16)(v2 >> 16));
  }
  if (i < i1) {
    const int e1 = perm[i];
    unsigned v1 = *(const unsigned*)(msg + (size_t)e1 * DD + lane * 2);
    a0 += bf2f((u16)(v1 & 0xFFFFu));
    a1 += bf2f((u16)(v1 >> 16));
  }
  float* ar = agg + (size_t)n * DD + lane * 2;
  ar[0] = a0;
  ar[1] = a1;
}

// ---------------- one merged prep kernel ----------------
static __device__ __forceinline__ void wcvt(const float* src, u16* dst, int K, int b, int t) {
  int i = b * 256 + t;
  int n = i & 127;
  int k = (i >> 7) % K;
  int sl = i / (K * 128);
  dst[((size_t)sl * 128 + n) * K + k] = f2bf(src[i]);
}

__global__ void prep_kernel(
    const float* __restrict__ eW0, const float* __restrict__ eW1, const float* __restrict__ eW2,
    const float* __restrict__ nW0, const float* __restrict__ nW1, const float* __restrict__ nW2,
    u16* __restrict__ eW0T, u16* __restrict__ eW1T, u16* __restrict__ eW2T,
    u16* __restrict__ nW0T, u16* __restrict__ nW1T, u16* __restrict__ nW2T,
    int* __restrict__ deg_m, int* __restrict__ deg_o,
    const float* __restrict__ xm, const float* __restrict__ xo,
    float* __restrict__ xf, u16* __restrict__ xmb, u16* __restrict__ xob)
{
  const int b = blockIdx.x, t = threadIdx.x;
  if (b < 768)        wcvt(eW0, eW0T, 384, b, t);
  else if (b < 1024)  wcvt(eW1, eW1T, 128, b - 768, t);
  else if (b < 1280)  wcvt(eW2, eW2T, 128, b - 1024, t);
  else if (b < 1792)  wcvt(nW0, nW0T, 256, b - 1280, t);
  else if (b < 2048)  wcvt(nW1, nW1T, 128, b - 1792, t);
  else if (b < 2304)  wcvt(nW2, nW2T, 128, b - 2048, t);
  else if (b < 2429) {
    int i = (b - 2304) * 256 + t;
    if (i < NMESH) deg_m[i] = 0;
    else if (i < NMESH + NOBJ) deg_o[i - NMESH] = 0;
  } else {
    int i = (b - 2429) * 256 + t;
    const int tm = NMESH * DD;
    if (i < tm) { float v = xm[i]; xf[i] = v; xmb[i] = f2bf(v); }
    else { int j = i - tm; float v = xo[j]; xf[tm + j] = v; xob[j] = f2bf(v); }
  }
}

extern "C" void kernel_launch(void* const* d_in, const int* in_sizes, int n_in,
                              void* d_out, int out_size, void* d_ws, size_t ws_size,
                              hipStream_t stream)
{
  const float* x_mesh = (const float*)d_in[0];
  const float* x_obj  = (const float*)d_in[1];
  const int*   ei_mm  = (const int*)d_in[2];
  const int*   ei_mo  = (const int*)d_in[3];
  const float* ea_mm  = (const float*)d_in[4];
  const float* ea_mo  = (const float*)d_in[5];
  const float* eW0 = (const float*)d_in[6];
  const float* eb0 = (const float*)d_in[7];
  const float* eW1 = (const float*)d_in[8];
  const float* eb1 = (const float*)d_in[9];
  const float* eW2 = (const float*)d_in[10];
  const float* eb2 = (const float*)d_in[11];
  const float* eg  = (const float*)d_in[12];
  const float* ebt = (const float*)d_in[13];
  const float* nW0 = (const float*)d_in[14];
  const float* nb0 = (const float*)d_in[15];
  const float* nW1 = (const float*)d_in[16];
  const float* nb1 = (const float*)d_in[17];
  const float* nW2 = (const float*)d_in[18];
  const float* nb2 = (const float*)d_in[19];
  const float* ng  = (const float*)d_in[20];
  const float* nbt = (const float*)d_in[21];

  u16* eamm_bf = (u16*)d_ws;
  u16* eamo_bf = eamm_bf + (size_t)EMMN * DD;
  u16* xm_bf   = eamo_bf + (size_t)EMON * DD;
  u16* xo_bf   = xm_bf + (size_t)NMESH * DD;
  float* agg_m = (float*)(xo_bf + (size_t)NOBJ * DD);
  float* agg_o = agg_m + (size_t)NMESH * DD;
  u16* eW0T = (u16*)(agg_o + (size_t)NOBJ * DD);
  u16* eW1T = eW0T + (size_t)4 * 128 * 384;
  u16* eW2T = eW1T + (size_t)4 * 128 * 128;
  u16* nW0T = eW2T + (size_t)4 * 128 * 128;
  u16* nW1T = nW0T + (size_t)4 * 128 * 256;
  u16* nW2T = nW1T + (size_t)4 * 128 * 128;
  u16* msg_mm = nW2T + (size_t)4 * 128 * 128;
  u16* msg_mo = msg_mm + (size_t)EMMN * DD;
  int* deg_m   = (int*)(msg_mo + (size_t)EMON * DD);
  int* start_m = deg_m + NMESH;
  int* cur_m   = start_m + NMESH + 1;
  int* perm_mm = cur_m + NMESH;
  int* deg_o   = perm_mm + EMMN;
  int* start_o = deg_o + NOBJ;
  int* cur_o   = start_o + NOBJ + 1;
  int* perm_mo = cur_o + NOBJ;

  float* xf_m = (float*)d_out;
  float* xf_o = xf_m + (size_t)NMESH * DD;

  prep_kernel<<<18429, 256, 0, stream>>>(eW0, eW1, eW2, nW0, nW1, nW2,
                                         eW0T, eW1T, eW2T, nW0T, nW1T, nW2T,
                                         deg_m, deg_o, x_mesh, x_obj, xf_m, xm_bf, xo_bf);
  hist_kernel<<<(EMMN + EMON + 255) / 256, 256, 0, stream>>>(ei_mm, ei_mo, deg_m, deg_o);
  scan_kernel<<<2, 1024, 0, stream>>>(deg_m, start_m, cur_m, deg_o, start_o, cur_o);
  scatter_kernel<<<(EMMN + EMON + 255) / 256, 256, 0, stream>>>(ei_mm, ei_mo, cur_m, cur_o,
                                                                perm_mm, perm_mo);

  for (int s = 0; s < 2; ++s) {
    const int sa = 0 * 2 + s, sb = 1 * 2 + s;
    edge_conv_kernel<<<NB_MM + NB_MO, 512, 0, stream>>>(
        xm_bf, xo_bf, ei_mm, ei_mo,
        (s == 0) ? ea_mm : (const float*)nullptr,
        (s == 0) ? ea_mo : (const float*)nullptr,
        eamm_bf, eamo_bf,
        eW0T + (size_t)sa * 128 * 384, eW1T + (size_t)sa * 128 * 128, eW2T + (size_t)sa * 128 * 128,
        eW0T + (size_t)sb * 128 * 384, eW1T + (size_t)sb * 128 * 128, eW2T + (size_t)sb * 128 * 128,
        eb0 + sa * 128, eb1 + sa * 128, eb2 + sa * 128, eg + sa * 128, ebt + sa * 128,
        eb0 + sb * 128, eb1 + sb * 128, eb2 + sb * 128, eg + sb * 128, ebt + sb * 128,
        msg_mm, msg_mo);
    agg_gather_kernel<<<(NMESH + NOBJ + 3) / 4, 256, 0, stream>>>(
        msg_mm, start_m, perm_mm, agg_m, msg_mo, start_o, perm_mo, agg_o);
    node_conv_kernel<<<NB_NM + NB_NO, 512, 0, stream>>>(
        xm_bf, xo_bf, agg_m, agg_o, xf_m, xf_o,
        nW0T + (size_t)sa * 128 * 256, nW1T + (size_t)sa * 128 * 128, nW2T + (size_t)sa * 128 * 128,
        nW0T + (size_t)sb * 128 * 256, nW1T + (size_t)sb * 128 * 128, nW2T + (size_t)sb * 128 * 128,
        nb0 + sa * 128, nb1 + sa * 128, nb2 + sa * 128, ng + sa * 128, nbt + sa * 128,
        nb0 + sb * 128, nb1 + sb * 128, nb2 + sb * 128, ng + sb * 128, nbt + sb * 128);
  }
}